// Round 16
// baseline (376.733 us; speedup 1.0000x reference)
//
#include <hip/hip_runtime.h>

typedef __bf16 bf16;
typedef __attribute__((ext_vector_type(8))) __bf16 bf16x8;
typedef __attribute__((ext_vector_type(4))) float f32x4;

#define B_SZ 4
#define SEQ 2048
#define DM 1024
#define DIN 2048
#define NH 256
#define DSTATE 16
#define CONVD 2080
#define DPROJ 4384
#define NPAD1 4608
#define MROWS 8192
#define NC 32
#define LC 64
#define SLOTF 1056  // floats per scan-state slot (1024 S + 8 P, padded)

__device__ __forceinline__ void gload_lds16(const void* g, void* l) {
  __builtin_amdgcn_global_load_lds(
      (__attribute__((address_space(1))) void*)g,
      (__attribute__((address_space(3))) void*)l, 16, 0, 0);
}

template <int N>
__device__ __forceinline__ void vm_wait() {
  asm volatile("s_waitcnt vmcnt(%0)" ::"n"(N) : "memory");
}
__device__ __forceinline__ void bar() { asm volatile("s_barrier" ::: "memory"); }
__device__ __forceinline__ void lgkm0() {
  asm volatile("s_waitcnt lgkmcnt(0)" ::: "memory");
}

// ---------------- transpose (f32 [K][N] -> bf16 [Npad][K]); optional per-k row scale
__global__ void transpose_cvt(const float* __restrict__ W, bf16* __restrict__ WT,
                              int K, int N, int Npad, const float* __restrict__ rw) {
  __shared__ float tile[32][33];
  int k0 = blockIdx.x * 32, n0 = blockIdx.y * 32;
  int tx = threadIdx.x, ty = threadIdx.y;  // (32, 8)
#pragma unroll
  for (int j = 0; j < 4; j++) {
    int k = k0 + ty + 8 * j, n = n0 + tx;
    float v = (k < K && n < N) ? W[(size_t)k * N + n] : 0.f;
    if (rw && k < K) v *= rw[k];
    tile[ty + 8 * j][tx] = v;
  }
  __syncthreads();
#pragma unroll
  for (int j = 0; j < 4; j++) {
    int n = n0 + ty + 8 * j, k = k0 + tx;
    if (n < Npad && k < K) WT[(size_t)n * K + k] = (bf16)tile[tx][ty + 8 * j];
  }
}

// ---------------- layernorm (f32 in) -> xn bf16
__global__ __launch_bounds__(256) void ln_kernel(const float* __restrict__ x,
                                                 const float* __restrict__ lw,
                                                 const float* __restrict__ lb,
                                                 bf16* __restrict__ xn) {
  int row = blockIdx.x;
  int t = threadIdx.x;
  f32x4 v4 = ((const f32x4*)(x + (size_t)row * DM))[t];
  float v0 = v4[0], v1 = v4[1], v2 = v4[2], v3 = v4[3];
  float s = v0 + v1 + v2 + v3;
  float s2 = v0 * v0 + v1 * v1 + v2 * v2 + v3 * v3;
#pragma unroll
  for (int off = 32; off > 0; off >>= 1) {
    s += __shfl_down(s, off);
    s2 += __shfl_down(s2, off);
  }
  __shared__ float ps[8];
  int wave = t >> 6, lane = t & 63;
  if (lane == 0) { ps[wave] = s; ps[4 + wave] = s2; }
  __syncthreads();
  s = ps[0] + ps[1] + ps[2] + ps[3];
  s2 = ps[4] + ps[5] + ps[6] + ps[7];
  float mean = s * (1.f / DM);
  float var = s2 * (1.f / DM) - mean * mean;
  float rstd = rsqrtf(var + 1e-5f);
  f32x4 wv = ((const f32x4*)lw)[t];
  f32x4 bv = ((const f32x4*)lb)[t];
  bf16 o[4];
  o[0] = (bf16)((v0 - mean) * rstd * wv[0] + bv[0]);
  o[1] = (bf16)((v1 - mean) * rstd * wv[1] + bv[1]);
  o[2] = (bf16)((v2 - mean) * rstd * wv[2] + bv[2]);
  o[3] = (bf16)((v3 - mean) * rstd * wv[3] + bv[3]);
  bf16* dst = xn + (size_t)row * DM + t * 4;
  dst[0] = o[0]; dst[1] = o[1]; dst[2] = o[2]; dst[3] = o[3];
}

// ---------------- GEMM1: 256x192 tile, grid 768 (exactly 3 rounds), BK=64,
// 8 waves (2M x 4N). A double-buffered (2x32KB), B triple-buffered (3x24KB) = 136 KiB.
__global__ __launch_bounds__(512, 2) void gemm1_8p(const bf16* __restrict__ A,
                                                   const bf16* __restrict__ BT,
                                                   bf16* __restrict__ C) {
  __shared__ char lds[139264];
  int bid = blockIdx.x;  // 768 = 32 m-tiles * 24 n-tiles
  int xcd = bid & 7;
  int l = bid >> 3;             // 0..95 per XCD, 32 per round
  int bm = xcd * 4 + ((l >> 3) & 3);
  int bn = (l >> 5) * 8 + (l & 7);
  int m0 = bm * 256, n0 = bn * 192;
  int t = threadIdx.x, lane = t & 63, wave = t >> 6;
  int wm = wave >> 2, wn = wave & 3;
  int lr16 = lane & 15, kq = lane >> 4;
  int ts0 = kq ^ (lr16 & 7);
  int ts1 = (4 + kq) ^ (lr16 & 7);
  int sw = (lane & 7) ^ (lane >> 3);
  int l8 = lane >> 3;
  const char* Ab = (const char*)A;
  const char* Bb = (const char*)BT;

  auto stA = [&](int kt) {
    char* slot = lds + (kt & 1) * 32768;
    size_t ko = (size_t)kt * 128 + sw * 16;
#pragma unroll
    for (int g = 0; g < 4; g++) {
      int c = wave * 4 + g;
      gload_lds16(Ab + (size_t)(m0 + c * 8 + l8) * 2048 + ko, slot + c * 1024);
    }
  };
  auto stB = [&](int kt) {
    char* slot = lds + 65536 + (kt % 3) * 24576;
    size_t ko = (size_t)kt * 128 + sw * 16;
#pragma unroll
    for (int g = 0; g < 3; g++) {
      int c = wave * 3 + g;
      gload_lds16(Bb + (size_t)(n0 + c * 8 + l8) * 2048 + ko, slot + c * 1024);
    }
  };

  f32x4 acc[8][3] = {};
  bf16x8 a_[4][2], b_[3][2];

  stA(0); stB(0); stA(1); stB(1);
  vm_wait<7>();
  bar();
#pragma unroll 1
  for (int kt = 0; kt < 16; kt++) {
    {
      const char* sa = lds + (kt & 1) * 32768;
      const char* sb = lds + 65536 + (kt % 3) * 24576;
#pragma unroll
      for (int mi = 0; mi < 4; mi++) {
        int lrow = wm * 128 + mi * 16 + lr16;
        a_[mi][0] = *(const bf16x8*)(sa + lrow * 128 + ts0 * 16);
        a_[mi][1] = *(const bf16x8*)(sa + lrow * 128 + ts1 * 16);
      }
#pragma unroll
      for (int ni = 0; ni < 3; ni++) {
        int lrow = wn * 48 + ni * 16 + lr16;
        b_[ni][0] = *(const bf16x8*)(sb + lrow * 128 + ts0 * 16);
        b_[ni][1] = *(const bf16x8*)(sb + lrow * 128 + ts1 * 16);
      }
      if (kt >= 1 && kt < 15) stA(kt + 1);
      if (kt < 14) stB(kt + 2);
      bar();
      lgkm0();
      __builtin_amdgcn_s_setprio(1);
#pragma unroll
      for (int mi = 0; mi < 4; mi++)
#pragma unroll
        for (int ni = 0; ni < 3; ni++) {
          acc[mi][ni] = __builtin_amdgcn_mfma_f32_16x16x32_bf16(a_[mi][0], b_[ni][0], acc[mi][ni], 0, 0, 0);
          acc[mi][ni] = __builtin_amdgcn_mfma_f32_16x16x32_bf16(a_[mi][1], b_[ni][1], acc[mi][ni], 0, 0, 0);
        }
      __builtin_amdgcn_s_setprio(0);
      bar();
    }
    {
      const char* sa = lds + (kt & 1) * 32768;
#pragma unroll
      for (int mi = 0; mi < 4; mi++) {
        int lrow = wm * 128 + 64 + mi * 16 + lr16;
        a_[mi][0] = *(const bf16x8*)(sa + lrow * 128 + ts0 * 16);
        a_[mi][1] = *(const bf16x8*)(sa + lrow * 128 + ts1 * 16);
      }
      if (kt <= 13) vm_wait<3>();
      else if (kt == 14) vm_wait<0>();
      bar();
      lgkm0();
      __builtin_amdgcn_s_setprio(1);
#pragma unroll
      for (int mi = 0; mi < 4; mi++)
#pragma unroll
        for (int ni = 0; ni < 3; ni++) {
          acc[4 + mi][ni] = __builtin_amdgcn_mfma_f32_16x16x32_bf16(a_[mi][0], b_[ni][0], acc[4 + mi][ni], 0, 0, 0);
          acc[4 + mi][ni] = __builtin_amdgcn_mfma_f32_16x16x32_bf16(a_[mi][1], b_[ni][1], acc[4 + mi][ni], 0, 0, 0);
        }
      __builtin_amdgcn_s_setprio(0);
      bar();
    }
  }
#pragma unroll
  for (int fr = 0; fr < 8; fr++)
#pragma unroll
    for (int ni = 0; ni < 3; ni++) {
      int row = m0 + wm * 128 + fr * 16 + kq * 4;
      int col = n0 + wn * 48 + ni * 16 + lr16;
      f32x4 v = acc[fr][ni];
      if (col < 4384) {
#pragma unroll
        for (int r = 0; r < 4; r++)
          C[(size_t)(row + r) * DPROJ + col] = (bf16)v[r];
      }
    }
}

// ---------------- GEMM2: 128x256 tile, BK=64, 8 waves (2M x 4N), grid 256.
// A = g_raw; fused RMSNorm (rms_w folded into WoutT; s2 from A-fragments).
__global__ __launch_bounds__(512, 2) void gemm2_8p(const bf16* __restrict__ A,
                                                   const bf16* __restrict__ BT,
                                                   float* __restrict__ C,
                                                   const float* __restrict__ Xres) {
  __shared__ char lds[147456];
  int bid = blockIdx.x;                  // 256 = 64 m * 4 n
  int swz = (bid & 7) * 32 + (bid >> 3); // bijective (256 % 8 == 0)
  int bm = swz >> 2, bn = swz & 3;
  int m0 = bm * 128, n0 = bn * 256;
  int t = threadIdx.x, lane = t & 63, wave = t >> 6;
  int wm = wave >> 2, wn = wave & 3;
  int lr16 = lane & 15, kq = lane >> 4;
  int ts0 = kq ^ (lr16 & 7);
  int ts1 = (4 + kq) ^ (lr16 & 7);
  int sw = (lane & 7) ^ (lane >> 3);
  int l8 = lane >> 3;
  const char* Ab = (const char*)A;
  const char* Bb = (const char*)BT;

  auto stA = [&](int kt) {
    char* slot = lds + (kt % 3) * 16384;
    size_t ko = (size_t)kt * 128 + sw * 16;
#pragma unroll
    for (int g = 0; g < 2; g++) {
      int c = wave * 2 + g;
      gload_lds16(Ab + (size_t)(m0 + c * 8 + l8) * 4096 + ko, slot + c * 1024);
    }
  };
  auto stB = [&](int kt) {
    char* slot = lds + 49152 + (kt % 3) * 32768;
    size_t ko = (size_t)kt * 128 + sw * 16;
#pragma unroll
    for (int g = 0; g < 4; g++) {
      int c = wave * 4 + g;
      gload_lds16(Bb + (size_t)(n0 + c * 8 + l8) * 4096 + ko, slot + c * 1024);
    }
  };

  f32x4 acc[4][4] = {};
  bf16x8 a_[4][2], b_[2][2];
  float s2a[4] = {0.f, 0.f, 0.f, 0.f};

  stA(0); stB(0); stA(1); stB(1);
  vm_wait<6>();
  bar();
#pragma unroll 1
  for (int kt = 0; kt < 32; kt++) {
    const char* sa = lds + (kt % 3) * 16384;
    const char* sb = lds + 49152 + (kt % 3) * 32768;
    {
#pragma unroll
      for (int mi = 0; mi < 4; mi++) {
        int lrow = wm * 64 + mi * 16 + lr16;
        a_[mi][0] = *(const bf16x8*)(sa + lrow * 128 + ts0 * 16);
        a_[mi][1] = *(const bf16x8*)(sa + lrow * 128 + ts1 * 16);
      }
#pragma unroll
      for (int ni = 0; ni < 2; ni++) {
        int lrow = wn * 64 + ni * 16 + lr16;
        b_[ni][0] = *(const bf16x8*)(sb + lrow * 128 + ts0 * 16);
        b_[ni][1] = *(const bf16x8*)(sb + lrow * 128 + ts1 * 16);
      }
      if (kt + 2 < 32) { stA(kt + 2); stB(kt + 2); }
      bar();
      lgkm0();
      __builtin_amdgcn_s_setprio(1);
#pragma unroll
      for (int mi = 0; mi < 4; mi++)
#pragma unroll
        for (int ni = 0; ni < 2; ni++) {
          acc[mi][ni] = __builtin_amdgcn_mfma_f32_16x16x32_bf16(a_[mi][0], b_[ni][0], acc[mi][ni], 0, 0, 0);
          acc[mi][ni] = __builtin_amdgcn_mfma_f32_16x16x32_bf16(a_[mi][1], b_[ni][1], acc[mi][ni], 0, 0, 0);
        }
      __builtin_amdgcn_s_setprio(0);
      bar();
    }
    {
#pragma unroll
      for (int ni = 0; ni < 2; ni++) {
        int lrow = wn * 64 + (2 + ni) * 16 + lr16;
        b_[ni][0] = *(const bf16x8*)(sb + lrow * 128 + ts0 * 16);
        b_[ni][1] = *(const bf16x8*)(sb + lrow * 128 + ts1 * 16);
      }
      if (kt <= 29) vm_wait<6>();
      else if (kt == 30) vm_wait<0>();
      bar();
      lgkm0();
      __builtin_amdgcn_s_setprio(1);
#pragma unroll
      for (int mi = 0; mi < 4; mi++)
#pragma unroll
        for (int ni = 0; ni < 2; ni++) {
          acc[mi][2 + ni] = __builtin_amdgcn_mfma_f32_16x16x32_bf16(a_[mi][0], b_[ni][0], acc[mi][2 + ni], 0, 0, 0);
          acc[mi][2 + ni] = __builtin_amdgcn_mfma_f32_16x16x32_bf16(a_[mi][1], b_[ni][1], acc[mi][2 + ni], 0, 0, 0);
        }
      __builtin_amdgcn_s_setprio(0);
#pragma unroll
      for (int mi = 0; mi < 4; mi++) {
        float s = 0.f;
#pragma unroll
        for (int si = 0; si < 2; si++)
#pragma unroll
          for (int e = 0; e < 8; e++) {
            float v = (float)a_[mi][si][e];
            s += v * v;
          }
        s2a[mi] += s;
      }
      bar();
    }
  }
#pragma unroll
  for (int mi = 0; mi < 4; mi++) {
    s2a[mi] += __shfl_xor(s2a[mi], 16);
    s2a[mi] += __shfl_xor(s2a[mi], 32);
  }
  float* scaleL = (float*)lds;
  if (wn == 0 && kq == 0) {
#pragma unroll
    for (int mi = 0; mi < 4; mi++)
      scaleL[wm * 64 + mi * 16 + lr16] = rsqrtf(s2a[mi] * (1.f / 2048.f) + 1e-5f);
  }
  __syncthreads();
#pragma unroll
  for (int mi = 0; mi < 4; mi++)
#pragma unroll
    for (int ni = 0; ni < 4; ni++) {
      int rloc = wm * 64 + mi * 16 + kq * 4;
      int col = n0 + wn * 64 + ni * 16 + lr16;
      f32x4 v = acc[mi][ni];
#pragma unroll
      for (int r = 0; r < 4; r++) {
        float sc = scaleL[rloc + r];
        size_t o = (size_t)(m0 + rloc + r) * DM + col;
        C[o] = Xres[o] + sc * v[r];
      }
    }
}

// ---------------- conv for B/C columns only (u cols [4096,4128)) -> BC f32 [8192][32]
__global__ __launch_bounds__(256) void conv_bc(const bf16* __restrict__ u,
                                               const float* __restrict__ cw,
                                               const float* __restrict__ cb,
                                               float* __restrict__ BC) {
  int idx = blockIdx.x * 256 + threadIdx.x;  // 8192 * 4
  if (idx >= MROWS * 4) return;
  int row = idx >> 2, j = idx & 3;
  int t = row & (SEQ - 1);
  int cc = 2048 + j * 8;  // conv-channel base
  float acc[8];
#pragma unroll
  for (int i = 0; i < 8; i++) acc[i] = cb[cc + i];
  const bf16* ub = u + (size_t)row * DPROJ + DIN + cc;
#pragma unroll
  for (int tap = 0; tap < 4; tap++) {
    if (t - 3 + tap >= 0) {
      bf16x8 uv = *(const bf16x8*)(ub + (ptrdiff_t)(tap - 3) * DPROJ);
      const float* wv = cw + tap * CONVD + cc;
#pragma unroll
      for (int i = 0; i < 8; i++) acc[i] += wv[i] * (float)uv[i];
    }
  }
  float* bc = BC + (size_t)row * 32 + j * 8;
#pragma unroll
  for (int i = 0; i < 8; i++) bc[i] = acc[i] / (1.f + __expf(-acc[i]));
}

// ---------------- scan p1 (fused conv+dt): local scan from zero -> (S,P) in scr
// block = (b, hg, c); lane owns conv channel hg*64+lane, head hg*8+(lane>>3)
__global__ __launch_bounds__(64) void scan_p1(const bf16* __restrict__ u,
                                              const float* __restrict__ BC,
                                              const float* __restrict__ A_log,
                                              const float* __restrict__ cw,
                                              const float* __restrict__ cb,
                                              const float* __restrict__ dt_bias,
                                              float* __restrict__ scr) {
  int c = blockIdx.x & 31, hg = (blockIdx.x >> 5) & 31, b = blockIdx.x >> 10;
  int lane = threadIdx.x, hh = lane >> 3;
  int h = hg * 8 + hh;
  int ch = hg * 64 + lane;
  float A = -__expf(A_log[h]);
  float dtbh = dt_bias[h];
  float w0 = cw[ch], w1 = cw[CONVD + ch], w2 = cw[2 * CONVD + ch], w3 = cw[3 * CONVD + ch];
  float cbc = cb[ch];
  size_t rb = (size_t)b * SEQ + (size_t)c * LC;
  const bf16* ux = u + rb * DPROJ + DIN + ch;
  const bf16* ud = u + rb * DPROJ + 4128 + h;
  float um3 = 0.f, um2 = 0.f, um1 = 0.f;
  if (c > 0) {
    um3 = (float)ux[-3 * (ptrdiff_t)DPROJ];
    um2 = (float)ux[-2 * (ptrdiff_t)DPROJ];
    um1 = (float)ux[-1 * (ptrdiff_t)DPROJ];
  }
  float st[16];
#pragma unroll
  for (int n = 0; n < 16; n++) st[n] = 0.f;
  float pcum = 1.f;
  for (int t = 0; t < LC; t++) {
    float uc = (float)ux[(size_t)t * DPROJ];
    float ca = cbc + w0 * um3 + w1 * um2 + w2 * um1 + w3 * uc;
    um3 = um2; um2 = um1; um1 = uc;
    float x = ca / (1.f + __expf(-ca));
    float dv = (float)ud[(size_t)t * DPROJ] + dtbh;
    float dtv = (dv > 20.f) ? dv : log1pf(__expf(dv));
    const float* bcrow = BC + (rb + t) * 32;
    float dA = __expf(dtv * A);
    pcum *= dA;
    float w = dtv * x;
#pragma unroll
    for (int n = 0; n < 16; n++) st[n] = st[n] * dA + w * bcrow[n];
  }
  float* S = scr + (size_t)blockIdx.x * SLOTF;
#pragma unroll
  for (int n = 0; n < 16; n++) S[lane * 16 + n] = st[n];
  if ((lane & 7) == 0) S[1024 + hh] = pcum;
}

// ---------------- p2: sequential combine over 32 chunks; S <- incoming H
__global__ __launch_bounds__(64) void scan_p2(float* __restrict__ scr) {
  int bh = blockIdx.x;  // 0..127 = b*32+hg
  int lane = threadIdx.x, hh = lane >> 3;
  float H[16];
#pragma unroll
  for (int n = 0; n < 16; n++) H[n] = 0.f;
  float* base = scr + (size_t)(bh * 32) * SLOTF;
  float sN[16], PN;
  {
#pragma unroll
    for (int n = 0; n < 16; n++) sN[n] = base[lane * 16 + n];
    PN = base[1024 + hh];
  }
  for (int c = 0; c < NC; c++) {
    float sC[16], PC = PN;
#pragma unroll
    for (int n = 0; n < 16; n++) sC[n] = sN[n];
    if (c + 1 < NC) {
      float* S = base + (size_t)(c + 1) * SLOTF;
#pragma unroll
      for (int n = 0; n < 16; n++) sN[n] = S[lane * 16 + n];
      PN = S[1024 + hh];
    }
    float* S0 = base + (size_t)c * SLOTF;
#pragma unroll
    for (int n = 0; n < 16; n++) {
      float hn = H[n];
      S0[lane * 16 + n] = hn;
      H[n] = PC * hn + sC[n];
    }
  }
}

// ---------------- p3 (fused conv+dt+gate): re-scan chunk, g_raw = (yv+D*x)*silu(z)
__global__ __launch_bounds__(64) void scan_p3(const bf16* __restrict__ u,
                                              const float* __restrict__ BC,
                                              const float* __restrict__ A_log,
                                              const float* __restrict__ Dp,
                                              const float* __restrict__ cw,
                                              const float* __restrict__ cb,
                                              const float* __restrict__ dt_bias,
                                              const float* __restrict__ scr,
                                              bf16* __restrict__ g) {
  int c = blockIdx.x & 31, hg = (blockIdx.x >> 5) & 31, b = blockIdx.x >> 10;
  int lane = threadIdx.x, hh = lane >> 3;
  int h = hg * 8 + hh;
  int ch = hg * 64 + lane;
  float A = -__expf(A_log[h]);
  float D = Dp[h];
  float dtbh = dt_bias[h];
  float w0 = cw[ch], w1 = cw[CONVD + ch], w2 = cw[2 * CONVD + ch], w3 = cw[3 * CONVD + ch];
  float cbc = cb[ch];
  size_t rb = (size_t)b * SEQ + (size_t)c * LC;
  const bf16* ux = u + rb * DPROJ + DIN + ch;
  const bf16* ud = u + rb * DPROJ + 4128 + h;
  const bf16* uz = u + rb * DPROJ + ch;
  float um3 = 0.f, um2 = 0.f, um1 = 0.f;
  if (c > 0) {
    um3 = (float)ux[-3 * (ptrdiff_t)DPROJ];
    um2 = (float)ux[-2 * (ptrdiff_t)DPROJ];
    um1 = (float)ux[-1 * (ptrdiff_t)DPROJ];
  }
  const float* S = scr + (size_t)blockIdx.x * SLOTF;
  float st[16];
#pragma unroll
  for (int n = 0; n < 16; n++) st[n] = S[lane * 16 + n];
  for (int t = 0; t < LC; t++) {
    float uc = (float)ux[(size_t)t * DPROJ];
    float ca = cbc + w0 * um3 + w1 * um2 + w2 * um1 + w3 * uc;
    um3 = um2; um2 = um1; um1 = uc;
    float x = ca / (1.f + __expf(-ca));
    float dv = (float)ud[(size_t)t * DPROJ] + dtbh;
    float dtv = (dv > 20.f) ? dv : log1pf(__expf(dv));
    const float* bcrow = BC + (rb + t) * 32;
    float dA = __expf(dtv * A);
    float w = dtv * x;
    float yv = 0.f;
#pragma unroll
    for (int n = 0; n < 16; n++) {
      st[n] = st[n] * dA + w * bcrow[n];
      yv += st[n] * bcrow[16 + n];
    }
    float z = (float)uz[(size_t)t * DPROJ];
    float gg = (yv + D * x) * (z / (1.f + __expf(-z)));
    g[(rb + t) * DIN + ch] = (bf16)gg;
  }
}

extern "C" void kernel_launch(void* const* d_in, const int* in_sizes, int n_in,
                              void* d_out, int out_size, void* d_ws, size_t ws_size,
                              hipStream_t stream) {
  const float* x = (const float*)d_in[0];
  const float* lnw = (const float*)d_in[1];
  const float* lnb = (const float*)d_in[2];
  const float* Win = (const float*)d_in[3];
  const float* cw = (const float*)d_in[4];
  const float* cb = (const float*)d_in[5];
  const float* Alog = (const float*)d_in[6];
  const float* Dpv = (const float*)d_in[7];
  const float* dtb = (const float*)d_in[8];
  const float* rmsw = (const float*)d_in[9];
  const float* Wout = (const float*)d_in[10];
  float* out = (float*)d_out;

  char* ws = (char*)d_ws;
  bf16* u = (bf16*)(ws + 0);                     // [8192][4384] bf16
  bf16* xnb = (bf16*)(ws + 71827456);            // [8192][1024] bf16 (dead after GEMM1)
  bf16* WinT = (bf16*)(ws + 88604672);           // [4608][1024] bf16 (dead after GEMM1)
  bf16* gb = (bf16*)(ws + 71827456);             // [8192][2048] bf16 g_raw (reuses xnb+WinT)
  float* scr = (float*)(ws + 105381888);         // [4096][1056] f32 scan state (17.3 MB)
  float* BC = (float*)(ws + 138936320);          // [8192][32] f32
  bf16* WoutT = (bf16*)(ws + 148373504);         // [1024][2048] bf16 (rms_w folded)

  transpose_cvt<<<dim3(32, 144), dim3(32, 8), 0, stream>>>(Win, WinT, 1024, DPROJ, NPAD1, nullptr);
  transpose_cvt<<<dim3(64, 32), dim3(32, 8), 0, stream>>>(Wout, WoutT, DIN, DM, DM, rmsw);
  ln_kernel<<<MROWS, 256, 0, stream>>>(x, lnw, lnb, xnb);
  gemm1_8p<<<768, 512, 0, stream>>>(xnb, WinT, u);
  conv_bc<<<(MROWS * 4) / 256, 256, 0, stream>>>(u, cw, cb, BC);
  scan_p1<<<4096, 64, 0, stream>>>(u, BC, Alog, cw, cb, dtb, scr);
  scan_p2<<<128, 64, 0, stream>>>(scr);
  scan_p3<<<4096, 64, 0, stream>>>(u, BC, Alog, Dpv, cw, cb, dtb, scr, gb);
  gemm2_8p<<<256, 512, 0, stream>>>(gb, WoutT, out, x);
}

// Round 17
// 291.274 us; speedup vs baseline: 1.2934x; 1.2934x over previous
//
#include <hip/hip_runtime.h>

typedef __bf16 bf16;
typedef __attribute__((ext_vector_type(8))) __bf16 bf16x8;
typedef __attribute__((ext_vector_type(4))) float f32x4;

#define B_SZ 4
#define SEQ 2048
#define DM 1024
#define DIN 2048
#define NH 256
#define DSTATE 16
#define CONVD 2080
#define DPROJ 4384
#define NPAD1 4608
#define MROWS 8192
#define NC 32
#define LC 64
#define UROWB 8768  // u row stride in bytes (4384 * 2)

__device__ __forceinline__ void gload_lds16(const void* g, void* l) {
  __builtin_amdgcn_global_load_lds(
      (__attribute__((address_space(1))) void*)g,
      (__attribute__((address_space(3))) void*)l, 16, 0, 0);
}

template <int N>
__device__ __forceinline__ void vm_wait() {
  asm volatile("s_waitcnt vmcnt(%0)" ::"n"(N) : "memory");
}
__device__ __forceinline__ void bar() { asm volatile("s_barrier" ::: "memory"); }
__device__ __forceinline__ void lgkm0() {
  asm volatile("s_waitcnt lgkmcnt(0)" ::: "memory");
}

// ---------------- both weight transposes in one launch (z selects which)
// z=0: Win f32[1024][4384] -> WinT bf16[4608][1024]
// z=1: Wout f32[2048][1024] * rmsw[k] -> WoutT bf16[1024][2048]
__global__ void transpose_both(const float* __restrict__ W0, bf16* __restrict__ T0,
                               const float* __restrict__ W1, bf16* __restrict__ T1,
                               const float* __restrict__ rw1) {
  const float* W; bf16* WT; int K, N, Npad; const float* rw;
  if (blockIdx.z == 0) { W = W0; WT = T0; K = 1024; N = DPROJ; Npad = NPAD1; rw = nullptr; }
  else { W = W1; WT = T1; K = DIN; N = DM; Npad = DM; rw = rw1; }
  int k0 = blockIdx.x * 32, n0 = blockIdx.y * 32;
  if (k0 >= K || n0 >= Npad) return;  // block-uniform exit, no sync hazard
  __shared__ float tile[32][33];
  int tx = threadIdx.x, ty = threadIdx.y;  // (32, 8)
#pragma unroll
  for (int j = 0; j < 4; j++) {
    int k = k0 + ty + 8 * j, n = n0 + tx;
    float v = (k < K && n < N) ? W[(size_t)k * N + n] : 0.f;
    if (rw && k < K) v *= rw[k];
    tile[ty + 8 * j][tx] = v;
  }
  __syncthreads();
#pragma unroll
  for (int j = 0; j < 4; j++) {
    int n = n0 + ty + 8 * j, k = k0 + tx;
    if (n < Npad && k < K) WT[(size_t)n * K + k] = (bf16)tile[tx][ty + 8 * j];
  }
}

// ---------------- layernorm (f32 in) -> xn bf16
__global__ __launch_bounds__(256) void ln_kernel(const float* __restrict__ x,
                                                 const float* __restrict__ lw,
                                                 const float* __restrict__ lb,
                                                 bf16* __restrict__ xn) {
  int row = blockIdx.x;
  int t = threadIdx.x;
  f32x4 v4 = ((const f32x4*)(x + (size_t)row * DM))[t];
  float v0 = v4[0], v1 = v4[1], v2 = v4[2], v3 = v4[3];
  float s = v0 + v1 + v2 + v3;
  float s2 = v0 * v0 + v1 * v1 + v2 * v2 + v3 * v3;
#pragma unroll
  for (int off = 32; off > 0; off >>= 1) {
    s += __shfl_down(s, off);
    s2 += __shfl_down(s2, off);
  }
  __shared__ float ps[8];
  int wave = t >> 6, lane = t & 63;
  if (lane == 0) { ps[wave] = s; ps[4 + wave] = s2; }
  __syncthreads();
  s = ps[0] + ps[1] + ps[2] + ps[3];
  s2 = ps[4] + ps[5] + ps[6] + ps[7];
  float mean = s * (1.f / DM);
  float var = s2 * (1.f / DM) - mean * mean;
  float rstd = rsqrtf(var + 1e-5f);
  f32x4 wv = ((const f32x4*)lw)[t];
  f32x4 bv = ((const f32x4*)lb)[t];
  bf16 o[4];
  o[0] = (bf16)((v0 - mean) * rstd * wv[0] + bv[0]);
  o[1] = (bf16)((v1 - mean) * rstd * wv[1] + bv[1]);
  o[2] = (bf16)((v2 - mean) * rstd * wv[2] + bv[2]);
  o[3] = (bf16)((v3 - mean) * rstd * wv[3] + bv[3]);
  bf16* dst = xn + (size_t)row * DM + t * 4;
  dst[0] = o[0]; dst[1] = o[1]; dst[2] = o[2]; dst[3] = o[3];
}

// ---------------- GEMM1: 256x192 tile, grid 768 (exactly 3 rounds), BK=64,
// 8 waves (2M x 4N). A double-buffered (2x32KB), B triple-buffered (3x24KB) = 136 KiB.
__global__ __launch_bounds__(512, 2) void gemm1_8p(const bf16* __restrict__ A,
                                                   const bf16* __restrict__ BT,
                                                   bf16* __restrict__ C) {
  __shared__ char lds[139264];
  int bid = blockIdx.x;  // 768 = 32 m-tiles * 24 n-tiles
  int xcd = bid & 7;
  int l = bid >> 3;             // 0..95 per XCD, 32 per round
  int bm = xcd * 4 + ((l >> 3) & 3);
  int bn = (l >> 5) * 8 + (l & 7);
  int m0 = bm * 256, n0 = bn * 192;
  int t = threadIdx.x, lane = t & 63, wave = t >> 6;
  int wm = wave >> 2, wn = wave & 3;
  int lr16 = lane & 15, kq = lane >> 4;
  int ts0 = kq ^ (lr16 & 7);
  int ts1 = (4 + kq) ^ (lr16 & 7);
  int sw = (lane & 7) ^ (lane >> 3);
  int l8 = lane >> 3;
  const char* Ab = (const char*)A;
  const char* Bb = (const char*)BT;

  auto stA = [&](int kt) {
    char* slot = lds + (kt & 1) * 32768;
    size_t ko = (size_t)kt * 128 + sw * 16;
#pragma unroll
    for (int g = 0; g < 4; g++) {
      int c = wave * 4 + g;
      gload_lds16(Ab + (size_t)(m0 + c * 8 + l8) * 2048 + ko, slot + c * 1024);
    }
  };
  auto stB = [&](int kt) {
    char* slot = lds + 65536 + (kt % 3) * 24576;
    size_t ko = (size_t)kt * 128 + sw * 16;
#pragma unroll
    for (int g = 0; g < 3; g++) {
      int c = wave * 3 + g;
      gload_lds16(Bb + (size_t)(n0 + c * 8 + l8) * 2048 + ko, slot + c * 1024);
    }
  };

  f32x4 acc[8][3] = {};
  bf16x8 a_[4][2], b_[3][2];

  stA(0); stB(0); stA(1); stB(1);
  vm_wait<7>();
  bar();
#pragma unroll 1
  for (int kt = 0; kt < 16; kt++) {
    {
      const char* sa = lds + (kt & 1) * 32768;
      const char* sb = lds + 65536 + (kt % 3) * 24576;
#pragma unroll
      for (int mi = 0; mi < 4; mi++) {
        int lrow = wm * 128 + mi * 16 + lr16;
        a_[mi][0] = *(const bf16x8*)(sa + lrow * 128 + ts0 * 16);
        a_[mi][1] = *(const bf16x8*)(sa + lrow * 128 + ts1 * 16);
      }
#pragma unroll
      for (int ni = 0; ni < 3; ni++) {
        int lrow = wn * 48 + ni * 16 + lr16;
        b_[ni][0] = *(const bf16x8*)(sb + lrow * 128 + ts0 * 16);
        b_[ni][1] = *(const bf16x8*)(sb + lrow * 128 + ts1 * 16);
      }
      if (kt >= 1 && kt < 15) stA(kt + 1);
      if (kt < 14) stB(kt + 2);
      bar();
      lgkm0();
      __builtin_amdgcn_s_setprio(1);
#pragma unroll
      for (int mi = 0; mi < 4; mi++)
#pragma unroll
        for (int ni = 0; ni < 3; ni++) {
          acc[mi][ni] = __builtin_amdgcn_mfma_f32_16x16x32_bf16(a_[mi][0], b_[ni][0], acc[mi][ni], 0, 0, 0);
          acc[mi][ni] = __builtin_amdgcn_mfma_f32_16x16x32_bf16(a_[mi][1], b_[ni][1], acc[mi][ni], 0, 0, 0);
        }
      __builtin_amdgcn_s_setprio(0);
      bar();
    }
    {
      const char* sa = lds + (kt & 1) * 32768;
#pragma unroll
      for (int mi = 0; mi < 4; mi++) {
        int lrow = wm * 128 + 64 + mi * 16 + lr16;
        a_[mi][0] = *(const bf16x8*)(sa + lrow * 128 + ts0 * 16);
        a_[mi][1] = *(const bf16x8*)(sa + lrow * 128 + ts1 * 16);
      }
      if (kt <= 13) vm_wait<3>();
      else if (kt == 14) vm_wait<0>();
      bar();
      lgkm0();
      __builtin_amdgcn_s_setprio(1);
#pragma unroll
      for (int mi = 0; mi < 4; mi++)
#pragma unroll
        for (int ni = 0; ni < 3; ni++) {
          acc[4 + mi][ni] = __builtin_amdgcn_mfma_f32_16x16x32_bf16(a_[mi][0], b_[ni][0], acc[4 + mi][ni], 0, 0, 0);
          acc[4 + mi][ni] = __builtin_amdgcn_mfma_f32_16x16x32_bf16(a_[mi][1], b_[ni][1], acc[4 + mi][ni], 0, 0, 0);
        }
      __builtin_amdgcn_s_setprio(0);
      bar();
    }
  }
#pragma unroll
  for (int fr = 0; fr < 8; fr++)
#pragma unroll
    for (int ni = 0; ni < 3; ni++) {
      int row = m0 + wm * 128 + fr * 16 + kq * 4;
      int col = n0 + wn * 48 + ni * 16 + lr16;
      f32x4 v = acc[fr][ni];
      if (col < 4384) {
#pragma unroll
        for (int r = 0; r < 4; r++)
          C[(size_t)(row + r) * DPROJ + col] = (bf16)v[r];
      }
    }
}

// ---------------- GEMM2: 128x256 tile, BK=64, 8 waves (2M x 4N), grid 256.
// A = g_raw; fused RMSNorm (rms_w folded into WoutT; s2 from A-fragments).
__global__ __launch_bounds__(512, 2) void gemm2_8p(const bf16* __restrict__ A,
                                                   const bf16* __restrict__ BT,
                                                   float* __restrict__ C,
                                                   const float* __restrict__ Xres) {
  __shared__ char lds[147456];
  int bid = blockIdx.x;                  // 256 = 64 m * 4 n
  int swz = (bid & 7) * 32 + (bid >> 3); // bijective (256 % 8 == 0)
  int bm = swz >> 2, bn = swz & 3;
  int m0 = bm * 128, n0 = bn * 256;
  int t = threadIdx.x, lane = t & 63, wave = t >> 6;
  int wm = wave >> 2, wn = wave & 3;
  int lr16 = lane & 15, kq = lane >> 4;
  int ts0 = kq ^ (lr16 & 7);
  int ts1 = (4 + kq) ^ (lr16 & 7);
  int sw = (lane & 7) ^ (lane >> 3);
  int l8 = lane >> 3;
  const char* Ab = (const char*)A;
  const char* Bb = (const char*)BT;

  auto stA = [&](int kt) {
    char* slot = lds + (kt % 3) * 16384;
    size_t ko = (size_t)kt * 128 + sw * 16;
#pragma unroll
    for (int g = 0; g < 2; g++) {
      int c = wave * 2 + g;
      gload_lds16(Ab + (size_t)(m0 + c * 8 + l8) * 4096 + ko, slot + c * 1024);
    }
  };
  auto stB = [&](int kt) {
    char* slot = lds + 49152 + (kt % 3) * 32768;
    size_t ko = (size_t)kt * 128 + sw * 16;
#pragma unroll
    for (int g = 0; g < 4; g++) {
      int c = wave * 4 + g;
      gload_lds16(Bb + (size_t)(n0 + c * 8 + l8) * 4096 + ko, slot + c * 1024);
    }
  };

  f32x4 acc[4][4] = {};
  bf16x8 a_[4][2], b_[2][2];
  float s2a[4] = {0.f, 0.f, 0.f, 0.f};

  stA(0); stB(0); stA(1); stB(1);
  vm_wait<6>();
  bar();
#pragma unroll 1
  for (int kt = 0; kt < 32; kt++) {
    const char* sa = lds + (kt % 3) * 16384;
    const char* sb = lds + 49152 + (kt % 3) * 32768;
    {
#pragma unroll
      for (int mi = 0; mi < 4; mi++) {
        int lrow = wm * 64 + mi * 16 + lr16;
        a_[mi][0] = *(const bf16x8*)(sa + lrow * 128 + ts0 * 16);
        a_[mi][1] = *(const bf16x8*)(sa + lrow * 128 + ts1 * 16);
      }
#pragma unroll
      for (int ni = 0; ni < 2; ni++) {
        int lrow = wn * 64 + ni * 16 + lr16;
        b_[ni][0] = *(const bf16x8*)(sb + lrow * 128 + ts0 * 16);
        b_[ni][1] = *(const bf16x8*)(sb + lrow * 128 + ts1 * 16);
      }
      if (kt + 2 < 32) { stA(kt + 2); stB(kt + 2); }
      bar();
      lgkm0();
      __builtin_amdgcn_s_setprio(1);
#pragma unroll
      for (int mi = 0; mi < 4; mi++)
#pragma unroll
        for (int ni = 0; ni < 2; ni++) {
          acc[mi][ni] = __builtin_amdgcn_mfma_f32_16x16x32_bf16(a_[mi][0], b_[ni][0], acc[mi][ni], 0, 0, 0);
          acc[mi][ni] = __builtin_amdgcn_mfma_f32_16x16x32_bf16(a_[mi][1], b_[ni][1], acc[mi][ni], 0, 0, 0);
        }
      __builtin_amdgcn_s_setprio(0);
      bar();
    }
    {
#pragma unroll
      for (int ni = 0; ni < 2; ni++) {
        int lrow = wn * 64 + (2 + ni) * 16 + lr16;
        b_[ni][0] = *(const bf16x8*)(sb + lrow * 128 + ts0 * 16);
        b_[ni][1] = *(const bf16x8*)(sb + lrow * 128 + ts1 * 16);
      }
      if (kt <= 29) vm_wait<6>();
      else if (kt == 30) vm_wait<0>();
      bar();
      lgkm0();
      __builtin_amdgcn_s_setprio(1);
#pragma unroll
      for (int mi = 0; mi < 4; mi++)
#pragma unroll
        for (int ni = 0; ni < 2; ni++) {
          acc[mi][2 + ni] = __builtin_amdgcn_mfma_f32_16x16x32_bf16(a_[mi][0], b_[ni][0], acc[mi][2 + ni], 0, 0, 0);
          acc[mi][2 + ni] = __builtin_amdgcn_mfma_f32_16x16x32_bf16(a_[mi][1], b_[ni][1], acc[mi][2 + ni], 0, 0, 0);
        }
      __builtin_amdgcn_s_setprio(0);
#pragma unroll
      for (int mi = 0; mi < 4; mi++) {
        float s = 0.f;
#pragma unroll
        for (int si = 0; si < 2; si++)
#pragma unroll
          for (int e = 0; e < 8; e++) {
            float v = (float)a_[mi][si][e];
            s += v * v;
          }
        s2a[mi] += s;
      }
      bar();
    }
  }
#pragma unroll
  for (int mi = 0; mi < 4; mi++) {
    s2a[mi] += __shfl_xor(s2a[mi], 16);
    s2a[mi] += __shfl_xor(s2a[mi], 32);
  }
  float* scaleL = (float*)lds;
  if (wn == 0 && kq == 0) {
#pragma unroll
    for (int mi = 0; mi < 4; mi++)
      scaleL[wm * 64 + mi * 16 + lr16] = rsqrtf(s2a[mi] * (1.f / 2048.f) + 1e-5f);
  }
  __syncthreads();
#pragma unroll
  for (int mi = 0; mi < 4; mi++)
#pragma unroll
    for (int ni = 0; ni < 4; ni++) {
      int rloc = wm * 64 + mi * 16 + kq * 4;
      int col = n0 + wn * 64 + ni * 16 + lr16;
      f32x4 v = acc[mi][ni];
#pragma unroll
      for (int r = 0; r < 4; r++) {
        float sc = scaleL[rloc + r];
        size_t o = (size_t)(m0 + rloc + r) * DM + col;
        C[o] = Xres[o] + sc * v[r];
      }
    }
}

// ---------------- conv: one thread per 8-channel vector per row (wide precompute)
__global__ __launch_bounds__(256) void conv_prep3(const bf16* __restrict__ u,
                                                  const float* __restrict__ cw,
                                                  const float* __restrict__ cb,
                                                  const float* __restrict__ dt_bias,
                                                  bf16* __restrict__ xs,
                                                  float* __restrict__ BC,
                                                  float* __restrict__ dtf) {
  const int JPR = 292;  // 260 conv vec8 + 32 dt vec8
  int idx = blockIdx.x * 256 + threadIdx.x;
  if (idx >= MROWS * JPR) return;
  int row = idx / JPR;
  int j = idx - row * JPR;
  int t = row & (SEQ - 1);
  if (j < 260) {
    int c0 = j * 8;
    float acc[8];
#pragma unroll
    for (int i = 0; i < 8; i++) acc[i] = cb[c0 + i];
    const bf16* ub = u + (size_t)row * DPROJ + DIN + c0;
#pragma unroll
    for (int tap = 0; tap < 4; tap++) {
      int tt = t - 3 + tap;
      if (tt >= 0) {
        bf16x8 uv = *(const bf16x8*)(ub + (ptrdiff_t)(tap - 3) * DPROJ);
        const float* wv = cw + tap * CONVD + c0;
#pragma unroll
        for (int i = 0; i < 8; i++) acc[i] += wv[i] * (float)uv[i];
      }
    }
    if (c0 < DIN) {
      bf16x8 o;
#pragma unroll
      for (int i = 0; i < 8; i++) {
        float sv = acc[i] / (1.f + __expf(-acc[i]));
        o[i] = (bf16)sv;
      }
      *(bf16x8*)(xs + (size_t)row * DIN + c0) = o;
    } else {
      float* bc = BC + (size_t)row * 32 + (c0 - DIN);
#pragma unroll
      for (int i = 0; i < 8; i++) bc[i] = acc[i] / (1.f + __expf(-acc[i]));
    }
  } else {
    int h0 = (j - 260) * 8;
    bf16x8 uv = *(const bf16x8*)(u + (size_t)row * DPROJ + (DPROJ - NH) + h0);
    float* dst = dtf + (size_t)row * NH + h0;
#pragma unroll
    for (int i = 0; i < 8; i++) {
      float xv = (float)uv[i] + dt_bias[h0 + i];
      dst[i] = (xv > 20.f) ? xv : log1pf(__expf(xv));
    }
  }
}

// ---------------- chunked scan (LC=64, NC=32), phase 1: local scan -> (S, P) in u tail
__global__ __launch_bounds__(64) void scan_p1(const bf16* __restrict__ xs,
                                              const float* __restrict__ BC,
                                              const float* __restrict__ dtf,
                                              const float* __restrict__ A_log,
                                              bf16* __restrict__ uscr) {
  int c = blockIdx.x & 31, hg = (blockIdx.x >> 5) & 31, b = blockIdx.x >> 10;
  int lane = threadIdx.x, hh = lane >> 3;
  int h = hg * 8 + hh;
  float A = -__expf(A_log[h]);
  float st[16];
#pragma unroll
  for (int n = 0; n < 16; n++) st[n] = 0.f;
  float pcum = 1.f;
  size_t rb = (size_t)b * SEQ + (size_t)c * LC;
#pragma unroll 2
  for (int t = 0; t < LC; t++) {
    size_t row = rb + t;
    const float* bcrow = BC + row * 32;
    float dtv = dtf[row * NH + h];
    float x = (float)xs[row * DIN + hg * 64 + lane];
    float dA = __expf(dtv * A);
    pcum *= dA;
    float w = dtv * x;
#pragma unroll
    for (int n = 0; n < 16; n++) st[n] = st[n] * dA + w * bcrow[n];
  }
  char* slot = (char*)uscr + (size_t)blockIdx.x * UROWB + 4096;
  float* S = (float*)slot;
#pragma unroll
  for (int n = 0; n < 16; n++) S[lane * 16 + n] = st[n];
  if ((lane & 7) == 0) ((float*)(slot + 4096))[hh] = pcum;
}

// ---------------- phase 2: sequential combine over 32 chunks; S <- incoming H
__global__ __launch_bounds__(64) void scan_p2(bf16* __restrict__ uscr) {
  int bh = blockIdx.x;  // 0..127 = b*32+hg
  int lane = threadIdx.x, hh = lane >> 3;
  float H[16];
#pragma unroll
  for (int n = 0; n < 16; n++) H[n] = 0.f;
  char* base = (char*)uscr + (size_t)bh * NC * UROWB + 4096;
  float sN[16], PN;
  {
    float* S = (float*)base;
#pragma unroll
    for (int n = 0; n < 16; n++) sN[n] = S[lane * 16 + n];
    PN = ((const float*)(base + 4096))[hh];
  }
  for (int c = 0; c < NC; c++) {
    float sC[16], PC = PN;
#pragma unroll
    for (int n = 0; n < 16; n++) sC[n] = sN[n];
    if (c + 1 < NC) {
      char* slot = base + (size_t)(c + 1) * UROWB;
      float* S = (float*)slot;
#pragma unroll
      for (int n = 0; n < 16; n++) sN[n] = S[lane * 16 + n];
      PN = ((const float*)(slot + 4096))[hh];
    }
    float* S0 = (float*)(base + (size_t)c * UROWB);
#pragma unroll
    for (int n = 0; n < 16; n++) {
      float hn = H[n];
      S0[lane * 16 + n] = hn;
      H[n] = PC * hn + sC[n];
    }
  }
}

// ---------------- phase 3 (fused gate): re-scan chunk, g_raw = (yv + D*x)*silu(z)
__global__ __launch_bounds__(64) void scan_p3(const bf16* __restrict__ xs,
                                              const float* __restrict__ BC,
                                              const float* __restrict__ dtf,
                                              const float* __restrict__ A_log,
                                              const float* __restrict__ Dp,
                                              const bf16* __restrict__ u,
                                              bf16* __restrict__ g) {
  int c = blockIdx.x & 31, hg = (blockIdx.x >> 5) & 31, b = blockIdx.x >> 10;
  int lane = threadIdx.x, hh = lane >> 3;
  int h = hg * 8 + hh;
  float A = -__expf(A_log[h]);
  float D = Dp[h];
  const char* slot = (const char*)u + (size_t)blockIdx.x * UROWB + 4096;
  float st[16];
#pragma unroll
  for (int n = 0; n < 16; n++) st[n] = ((const float*)slot)[lane * 16 + n];
  size_t rb = (size_t)b * SEQ + (size_t)c * LC;
#pragma unroll 2
  for (int t = 0; t < LC; t++) {
    size_t row = rb + t;
    const float* bcrow = BC + row * 32;
    float dtv = dtf[row * NH + h];
    float x = (float)xs[row * DIN + hg * 64 + lane];
    float dA = __expf(dtv * A);
    float w = dtv * x;
    float yv = 0.f;
#pragma unroll
    for (int n = 0; n < 16; n++) {
      st[n] = st[n] * dA + w * bcrow[n];
      yv += st[n] * bcrow[16 + n];
    }
    float z = (float)u[row * DPROJ + hg * 64 + lane];
    float gg = (yv + D * x) * (z / (1.f + __expf(-z)));
    g[row * DIN + hg * 64 + lane] = (bf16)gg;
  }
}

extern "C" void kernel_launch(void* const* d_in, const int* in_sizes, int n_in,
                              void* d_out, int out_size, void* d_ws, size_t ws_size,
                              hipStream_t stream) {
  const float* x = (const float*)d_in[0];
  const float* lnw = (const float*)d_in[1];
  const float* lnb = (const float*)d_in[2];
  const float* Win = (const float*)d_in[3];
  const float* cw = (const float*)d_in[4];
  const float* cb = (const float*)d_in[5];
  const float* Alog = (const float*)d_in[6];
  const float* Dpv = (const float*)d_in[7];
  const float* dtb = (const float*)d_in[8];
  const float* rmsw = (const float*)d_in[9];
  const float* Wout = (const float*)d_in[10];
  float* out = (float*)d_out;

  char* ws = (char*)d_ws;
  bf16* u = (bf16*)(ws + 0);                     // [8192][4384] bf16
  bf16* xnb = (bf16*)(ws + 71827456);            // [8192][1024] bf16 (dead after GEMM1)
  bf16* WinT = (bf16*)(ws + 88604672);           // [4608][1024] bf16 (dead after GEMM1)
  bf16* gb = (bf16*)(ws + 71827456);             // [8192][2048] bf16 g_raw (reuses xnb+WinT)
  bf16* xsb = (bf16*)(ws + 105381888);           // [8192][2048] bf16
  float* BC = (float*)(ws + 138936320);          // [8192][32] f32
  float* dtf = (float*)(ws + 139984896);         // [8192][256] f32
  bf16* WoutT = (bf16*)(ws + 148373504);         // [1024][2048] bf16 (rms_w folded)

  transpose_both<<<dim3(64, 144, 2), dim3(32, 8), 0, stream>>>(Win, WinT, Wout, WoutT, rmsw);
  ln_kernel<<<MROWS, 256, 0, stream>>>(x, lnw, lnb, xnb);
  gemm1_8p<<<768, 512, 0, stream>>>(xnb, WinT, u);
  conv_prep3<<<(MROWS * 292) / 256, 256, 0, stream>>>(u, cw, cb, dtb, xsb, BC, dtf);
  scan_p1<<<4096, 64, 0, stream>>>(xsb, BC, dtf, Alog, u);
  scan_p2<<<128, 64, 0, stream>>>(u);
  scan_p3<<<4096, 64, 0, stream>>>(xsb, BC, dtf, Alog, Dpv, u, gb);
  gemm2_8p<<<256, 512, 0, stream>>>(gb, WoutT, out, x);
}

// Round 18
// 280.506 us; speedup vs baseline: 1.3430x; 1.0384x over previous
//
#include <hip/hip_runtime.h>

typedef __bf16 bf16;
typedef __attribute__((ext_vector_type(8))) __bf16 bf16x8;
typedef __attribute__((ext_vector_type(4))) float f32x4;

#define B_SZ 4
#define SEQ 2048
#define DM 1024
#define DIN 2048
#define NH 256
#define DSTATE 16
#define CONVD 2080
#define DPROJ 4384
#define NPAD1 4608
#define MROWS 8192
#define NC 32
#define LC 64
#define UROWB 8768  // u row stride in bytes (4384 * 2)

__device__ __forceinline__ void gload_lds16(const void* g, void* l) {
  __builtin_amdgcn_global_load_lds(
      (__attribute__((address_space(1))) void*)g,
      (__attribute__((address_space(3))) void*)l, 16, 0, 0);
}

template <int N>
__device__ __forceinline__ void vm_wait() {
  asm volatile("s_waitcnt vmcnt(%0)" ::"n"(N) : "memory");
}
__device__ __forceinline__ void bar() { asm volatile("s_barrier" ::: "memory"); }
__device__ __forceinline__ void lgkm0() {
  asm volatile("s_waitcnt lgkmcnt(0)" ::: "memory");
}

// ---------------- both weight transposes in one launch (z selects which)
__global__ void transpose_both(const float* __restrict__ W0, bf16* __restrict__ T0,
                               const float* __restrict__ W1, bf16* __restrict__ T1,
                               const float* __restrict__ rw1) {
  const float* W; bf16* WT; int K, N, Npad; const float* rw;
  if (blockIdx.z == 0) { W = W0; WT = T0; K = 1024; N = DPROJ; Npad = NPAD1; rw = nullptr; }
  else { W = W1; WT = T1; K = DIN; N = DM; Npad = DM; rw = rw1; }
  int k0 = blockIdx.x * 32, n0 = blockIdx.y * 32;
  if (k0 >= K || n0 >= Npad) return;  // block-uniform exit, no sync hazard
  __shared__ float tile[32][33];
  int tx = threadIdx.x, ty = threadIdx.y;  // (32, 8)
#pragma unroll
  for (int j = 0; j < 4; j++) {
    int k = k0 + ty + 8 * j, n = n0 + tx;
    float v = (k < K && n < N) ? W[(size_t)k * N + n] : 0.f;
    if (rw && k < K) v *= rw[k];
    tile[ty + 8 * j][tx] = v;
  }
  __syncthreads();
#pragma unroll
  for (int j = 0; j < 4; j++) {
    int n = n0 + ty + 8 * j, k = k0 + tx;
    if (n < Npad && k < K) WT[(size_t)n * K + k] = (bf16)tile[tx][ty + 8 * j];
  }
}

// ---------------- layernorm (f32 in) -> xn bf16
__global__ __launch_bounds__(256) void ln_kernel(const float* __restrict__ x,
                                                 const float* __restrict__ lw,
                                                 const float* __restrict__ lb,
                                                 bf16* __restrict__ xn) {
  int row = blockIdx.x;
  int t = threadIdx.x;
  f32x4 v4 = ((const f32x4*)(x + (size_t)row * DM))[t];
  float v0 = v4[0], v1 = v4[1], v2 = v4[2], v3 = v4[3];
  float s = v0 + v1 + v2 + v3;
  float s2 = v0 * v0 + v1 * v1 + v2 * v2 + v3 * v3;
#pragma unroll
  for (int off = 32; off > 0; off >>= 1) {
    s += __shfl_down(s, off);
    s2 += __shfl_down(s2, off);
  }
  __shared__ float ps[8];
  int wave = t >> 6, lane = t & 63;
  if (lane == 0) { ps[wave] = s; ps[4 + wave] = s2; }
  __syncthreads();
  s = ps[0] + ps[1] + ps[2] + ps[3];
  s2 = ps[4] + ps[5] + ps[6] + ps[7];
  float mean = s * (1.f / DM);
  float var = s2 * (1.f / DM) - mean * mean;
  float rstd = rsqrtf(var + 1e-5f);
  f32x4 wv = ((const f32x4*)lw)[t];
  f32x4 bv = ((const f32x4*)lb)[t];
  bf16 o[4];
  o[0] = (bf16)((v0 - mean) * rstd * wv[0] + bv[0]);
  o[1] = (bf16)((v1 - mean) * rstd * wv[1] + bv[1]);
  o[2] = (bf16)((v2 - mean) * rstd * wv[2] + bv[2]);
  o[3] = (bf16)((v3 - mean) * rstd * wv[3] + bv[3]);
  bf16* dst = xn + (size_t)row * DM + t * 4;
  dst[0] = o[0]; dst[1] = o[1]; dst[2] = o[2]; dst[3] = o[3];
}

// ---------------- GEMM1: 128x192 tile, grid 1536 (= 3 rounds at 2 blocks/CU), BK=64,
// 8 waves (2M x 4N, wave 64x48). LDS = A 2x16KB + B 2x24KB = 80KB exactly -> 2 blocks/CU.
// Depth-1 prefetch (tile kt+1 issued ph1(kt)); full drain vmcnt(0) at ph2 -- stall
// intended to be hidden by the co-resident block (m114 inter-block overlap).
__global__ __launch_bounds__(512, 2) void gemm1_8p(const bf16* __restrict__ A,
                                                   const bf16* __restrict__ BT,
                                                   bf16* __restrict__ C) {
  __shared__ char lds[81920];
  int bid = blockIdx.x;  // 1536 = 64 m-tiles * 24 n-tiles
  int xcd = bid & 7;
  int l = bid >> 3;             // 0..191
  int bm = xcd * 8 + (l & 7);
  int bn = l >> 3;
  int m0 = bm * 128, n0 = bn * 192;
  int t = threadIdx.x, lane = t & 63, wave = t >> 6;
  int wm = wave >> 2, wn = wave & 3;
  int lr16 = lane & 15, kq = lane >> 4;
  int ts0 = kq ^ (lr16 & 7);
  int ts1 = (4 + kq) ^ (lr16 & 7);
  int sw = (lane & 7) ^ (lane >> 3);
  int l8 = lane >> 3;
  const char* Ab = (const char*)A;
  const char* Bb = (const char*)BT;

  // A: 128 rows x 128B = 16KB/buf; 2 gloads/thread
  auto stA = [&](int kt) {
    char* slot = lds + (kt & 1) * 16384;
    size_t ko = (size_t)kt * 128 + sw * 16;
#pragma unroll
    for (int g = 0; g < 2; g++) {
      int c = wave * 2 + g;
      gload_lds16(Ab + (size_t)(m0 + c * 8 + l8) * 2048 + ko, slot + c * 1024);
    }
  };
  // B: 192 rows x 128B = 24KB/buf; 3 gloads/thread
  auto stB = [&](int kt) {
    char* slot = lds + 32768 + (kt & 1) * 24576;
    size_t ko = (size_t)kt * 128 + sw * 16;
#pragma unroll
    for (int g = 0; g < 3; g++) {
      int c = wave * 3 + g;
      gload_lds16(Bb + (size_t)(n0 + c * 8 + l8) * 2048 + ko, slot + c * 1024);
    }
  };

  f32x4 acc[4][3] = {};
  bf16x8 a_[2][2], b_[3][2];

  // prologue: tiles 0 and 1 (10 loads); drain tile0 (5), leave tile1 in flight
  stA(0); stB(0); stA(1); stB(1);
  vm_wait<5>();
  bar();
#pragma unroll 1
  for (int kt = 0; kt < 16; kt++) {
    const char* sa = lds + (kt & 1) * 16384;
    const char* sb = lds + 32768 + (kt & 1) * 24576;
    // ---- ph1: read aL (mi 0,1) + all B; issue tile kt+1 (kt>=1); 12 MFMA
    {
#pragma unroll
      for (int mi = 0; mi < 2; mi++) {
        int lrow = wm * 64 + mi * 16 + lr16;
        a_[mi][0] = *(const bf16x8*)(sa + lrow * 128 + ts0 * 16);
        a_[mi][1] = *(const bf16x8*)(sa + lrow * 128 + ts1 * 16);
      }
#pragma unroll
      for (int ni = 0; ni < 3; ni++) {
        int lrow = wn * 48 + ni * 16 + lr16;
        b_[ni][0] = *(const bf16x8*)(sb + lrow * 128 + ts0 * 16);
        b_[ni][1] = *(const bf16x8*)(sb + lrow * 128 + ts1 * 16);
      }
      if (kt >= 1 && kt < 15) { stA(kt + 1); stB(kt + 1); }
      bar();
      lgkm0();
      __builtin_amdgcn_s_setprio(1);
#pragma unroll
      for (int mi = 0; mi < 2; mi++)
#pragma unroll
        for (int ni = 0; ni < 3; ni++) {
          acc[mi][ni] = __builtin_amdgcn_mfma_f32_16x16x32_bf16(a_[mi][0], b_[ni][0], acc[mi][ni], 0, 0, 0);
          acc[mi][ni] = __builtin_amdgcn_mfma_f32_16x16x32_bf16(a_[mi][1], b_[ni][1], acc[mi][ni], 0, 0, 0);
        }
      __builtin_amdgcn_s_setprio(0);
      bar();
    }
    // ---- ph2: read aH (mi 2,3); drain next tile's loads; 12 MFMA
    {
#pragma unroll
      for (int mi = 0; mi < 2; mi++) {
        int lrow = wm * 64 + (2 + mi) * 16 + lr16;
        a_[mi][0] = *(const bf16x8*)(sa + lrow * 128 + ts0 * 16);
        a_[mi][1] = *(const bf16x8*)(sa + lrow * 128 + ts1 * 16);
      }
      if (kt < 15) vm_wait<0>();
      bar();
      lgkm0();
      __builtin_amdgcn_s_setprio(1);
#pragma unroll
      for (int mi = 0; mi < 2; mi++)
#pragma unroll
        for (int ni = 0; ni < 3; ni++) {
          acc[2 + mi][ni] = __builtin_amdgcn_mfma_f32_16x16x32_bf16(a_[mi][0], b_[ni][0], acc[2 + mi][ni], 0, 0, 0);
          acc[2 + mi][ni] = __builtin_amdgcn_mfma_f32_16x16x32_bf16(a_[mi][1], b_[ni][1], acc[2 + mi][ni], 0, 0, 0);
        }
      __builtin_amdgcn_s_setprio(0);
      bar();
    }
  }
#pragma unroll
  for (int fr = 0; fr < 4; fr++)
#pragma unroll
    for (int ni = 0; ni < 3; ni++) {
      int row = m0 + wm * 64 + fr * 16 + kq * 4;
      int col = n0 + wn * 48 + ni * 16 + lr16;
      f32x4 v = acc[fr][ni];
      if (col < 4384) {
#pragma unroll
        for (int r = 0; r < 4; r++)
          C[(size_t)(row + r) * DPROJ + col] = (bf16)v[r];
      }
    }
}

// ---------------- GEMM2: 128x256 tile, BK=64, 8 waves (2M x 4N), grid 256.
// A = g_raw; fused RMSNorm (rms_w folded into WoutT; s2 from A-fragments).
__global__ __launch_bounds__(512, 2) void gemm2_8p(const bf16* __restrict__ A,
                                                   const bf16* __restrict__ BT,
                                                   float* __restrict__ C,
                                                   const float* __restrict__ Xres) {
  __shared__ char lds[147456];
  int bid = blockIdx.x;                  // 256 = 64 m * 4 n
  int swz = (bid & 7) * 32 + (bid >> 3); // bijective (256 % 8 == 0)
  int bm = swz >> 2, bn = swz & 3;
  int m0 = bm * 128, n0 = bn * 256;
  int t = threadIdx.x, lane = t & 63, wave = t >> 6;
  int wm = wave >> 2, wn = wave & 3;
  int lr16 = lane & 15, kq = lane >> 4;
  int ts0 = kq ^ (lr16 & 7);
  int ts1 = (4 + kq) ^ (lr16 & 7);
  int sw = (lane & 7) ^ (lane >> 3);
  int l8 = lane >> 3;
  const char* Ab = (const char*)A;
  const char* Bb = (const char*)BT;

  auto stA = [&](int kt) {
    char* slot = lds + (kt % 3) * 16384;
    size_t ko = (size_t)kt * 128 + sw * 16;
#pragma unroll
    for (int g = 0; g < 2; g++) {
      int c = wave * 2 + g;
      gload_lds16(Ab + (size_t)(m0 + c * 8 + l8) * 4096 + ko, slot + c * 1024);
    }
  };
  auto stB = [&](int kt) {
    char* slot = lds + 49152 + (kt % 3) * 32768;
    size_t ko = (size_t)kt * 128 + sw * 16;
#pragma unroll
    for (int g = 0; g < 4; g++) {
      int c = wave * 4 + g;
      gload_lds16(Bb + (size_t)(n0 + c * 8 + l8) * 4096 + ko, slot + c * 1024);
    }
  };

  f32x4 acc[4][4] = {};
  bf16x8 a_[4][2], b_[2][2];
  float s2a[4] = {0.f, 0.f, 0.f, 0.f};

  stA(0); stB(0); stA(1); stB(1);
  vm_wait<6>();
  bar();
#pragma unroll 1
  for (int kt = 0; kt < 32; kt++) {
    const char* sa = lds + (kt % 3) * 16384;
    const char* sb = lds + 49152 + (kt % 3) * 32768;
    {
#pragma unroll
      for (int mi = 0; mi < 4; mi++) {
        int lrow = wm * 64 + mi * 16 + lr16;
        a_[mi][0] = *(const bf16x8*)(sa + lrow * 128 + ts0 * 16);
        a_[mi][1] = *(const bf16x8*)(sa + lrow * 128 + ts1 * 16);
      }
#pragma unroll
      for (int ni = 0; ni < 2; ni++) {
        int lrow = wn * 64 + ni * 16 + lr16;
        b_[ni][0] = *(const bf16x8*)(sb + lrow * 128 + ts0 * 16);
        b_[ni][1] = *(const bf16x8*)(sb + lrow * 128 + ts1 * 16);
      }
      if (kt + 2 < 32) { stA(kt + 2); stB(kt + 2); }
      bar();
      lgkm0();
      __builtin_amdgcn_s_setprio(1);
#pragma unroll
      for (int mi = 0; mi < 4; mi++)
#pragma unroll
        for (int ni = 0; ni < 2; ni++) {
          acc[mi][ni] = __builtin_amdgcn_mfma_f32_16x16x32_bf16(a_[mi][0], b_[ni][0], acc[mi][ni], 0, 0, 0);
          acc[mi][ni] = __builtin_amdgcn_mfma_f32_16x16x32_bf16(a_[mi][1], b_[ni][1], acc[mi][ni], 0, 0, 0);
        }
      __builtin_amdgcn_s_setprio(0);
      bar();
    }
    {
#pragma unroll
      for (int ni = 0; ni < 2; ni++) {
        int lrow = wn * 64 + (2 + ni) * 16 + lr16;
        b_[ni][0] = *(const bf16x8*)(sb + lrow * 128 + ts0 * 16);
        b_[ni][1] = *(const bf16x8*)(sb + lrow * 128 + ts1 * 16);
      }
      if (kt <= 29) vm_wait<6>();
      else if (kt == 30) vm_wait<0>();
      bar();
      lgkm0();
      __builtin_amdgcn_s_setprio(1);
#pragma unroll
      for (int mi = 0; mi < 4; mi++)
#pragma unroll
        for (int ni = 0; ni < 2; ni++) {
          acc[mi][2 + ni] = __builtin_amdgcn_mfma_f32_16x16x32_bf16(a_[mi][0], b_[ni][0], acc[mi][2 + ni], 0, 0, 0);
          acc[mi][2 + ni] = __builtin_amdgcn_mfma_f32_16x16x32_bf16(a_[mi][1], b_[ni][1], acc[mi][2 + ni], 0, 0, 0);
        }
      __builtin_amdgcn_s_setprio(0);
#pragma unroll
      for (int mi = 0; mi < 4; mi++) {
        float s = 0.f;
#pragma unroll
        for (int si = 0; si < 2; si++)
#pragma unroll
          for (int e = 0; e < 8; e++) {
            float v = (float)a_[mi][si][e];
            s += v * v;
          }
        s2a[mi] += s;
      }
      bar();
    }
  }
#pragma unroll
  for (int mi = 0; mi < 4; mi++) {
    s2a[mi] += __shfl_xor(s2a[mi], 16);
    s2a[mi] += __shfl_xor(s2a[mi], 32);
  }
  float* scaleL = (float*)lds;
  if (wn == 0 && kq == 0) {
#pragma unroll
    for (int mi = 0; mi < 4; mi++)
      scaleL[wm * 64 + mi * 16 + lr16] = rsqrtf(s2a[mi] * (1.f / 2048.f) + 1e-5f);
  }
  __syncthreads();
#pragma unroll
  for (int mi = 0; mi < 4; mi++)
#pragma unroll
    for (int ni = 0; ni < 4; ni++) {
      int rloc = wm * 64 + mi * 16 + kq * 4;
      int col = n0 + wn * 64 + ni * 16 + lr16;
      f32x4 v = acc[mi][ni];
#pragma unroll
      for (int r = 0; r < 4; r++) {
        float sc = scaleL[rloc + r];
        size_t o = (size_t)(m0 + rloc + r) * DM + col;
        C[o] = Xres[o] + sc * v[r];
      }
    }
}

// ---------------- conv: one thread per 8-channel vector per row (wide precompute)
__global__ __launch_bounds__(256) void conv_prep3(const bf16* __restrict__ u,
                                                  const float* __restrict__ cw,
                                                  const float* __restrict__ cb,
                                                  const float* __restrict__ dt_bias,
                                                  bf16* __restrict__ xs,
                                                  float* __restrict__ BC,
                                                  float* __restrict__ dtf) {
  const int JPR = 292;  // 260 conv vec8 + 32 dt vec8
  int idx = blockIdx.x * 256 + threadIdx.x;
  if (idx >= MROWS * JPR) return;
  int row = idx / JPR;
  int j = idx - row * JPR;
  int t = row & (SEQ - 1);
  if (j < 260) {
    int c0 = j * 8;
    float acc[8];
#pragma unroll
    for (int i = 0; i < 8; i++) acc[i] = cb[c0 + i];
    const bf16* ub = u + (size_t)row * DPROJ + DIN + c0;
#pragma unroll
    for (int tap = 0; tap < 4; tap++) {
      int tt = t - 3 + tap;
      if (tt >= 0) {
        bf16x8 uv = *(const bf16x8*)(ub + (ptrdiff_t)(tap - 3) * DPROJ);
        const float* wv = cw + tap * CONVD + c0;
#pragma unroll
        for (int i = 0; i < 8; i++) acc[i] += wv[i] * (float)uv[i];
      }
    }
    if (c0 < DIN) {
      bf16x8 o;
#pragma unroll
      for (int i = 0; i < 8; i++) {
        float sv = acc[i] / (1.f + __expf(-acc[i]));
        o[i] = (bf16)sv;
      }
      *(bf16x8*)(xs + (size_t)row * DIN + c0) = o;
    } else {
      float* bc = BC + (size_t)row * 32 + (c0 - DIN);
#pragma unroll
      for (int i = 0; i < 8; i++) bc[i] = acc[i] / (1.f + __expf(-acc[i]));
    }
  } else {
    int h0 = (j - 260) * 8;
    bf16x8 uv = *(const bf16x8*)(u + (size_t)row * DPROJ + (DPROJ - NH) + h0);
    float* dst = dtf + (size_t)row * NH + h0;
#pragma unroll
    for (int i = 0; i < 8; i++) {
      float xv = (float)uv[i] + dt_bias[h0 + i];
      dst[i] = (xv > 20.f) ? xv : log1pf(__expf(xv));
    }
  }
}

// ---------------- chunked scan (LC=64, NC=32), phase 1: local scan -> (S, P) in u tail
__global__ __launch_bounds__(64) void scan_p1(const bf16* __restrict__ xs,
                                              const float* __restrict__ BC,
                                              const float* __restrict__ dtf,
                                              const float* __restrict__ A_log,
                                              bf16* __restrict__ uscr) {
  int c = blockIdx.x & 31, hg = (blockIdx.x >> 5) & 31, b = blockIdx.x >> 10;
  int lane = threadIdx.x, hh = lane >> 3;
  int h = hg * 8 + hh;
  float A = -__expf(A_log[h]);
  float st[16];
#pragma unroll
  for (int n = 0; n < 16; n++) st[n] = 0.f;
  float pcum = 1.f;
  size_t rb = (size_t)b * SEQ + (size_t)c * LC;
#pragma unroll 2
  for (int t = 0; t < LC; t++) {
    size_t row = rb + t;
    const float* bcrow = BC + row * 32;
    float dtv = dtf[row * NH + h];
    float x = (float)xs[row * DIN + hg * 64 + lane];
    float dA = __expf(dtv * A);
    pcum *= dA;
    float w = dtv * x;
#pragma unroll
    for (int n = 0; n < 16; n++) st[n] = st[n] * dA + w * bcrow[n];
  }
  char* slot = (char*)uscr + (size_t)blockIdx.x * UROWB + 4096;
  float* S = (float*)slot;
#pragma unroll
  for (int n = 0; n < 16; n++) S[lane * 16 + n] = st[n];
  if ((lane & 7) == 0) ((float*)(slot + 4096))[hh] = pcum;
}

// ---------------- phase 2: sequential combine over 32 chunks; S <- incoming H
__global__ __launch_bounds__(64) void scan_p2(bf16* __restrict__ uscr) {
  int bh = blockIdx.x;  // 0..127 = b*32+hg
  int lane = threadIdx.x, hh = lane >> 3;
  float H[16];
#pragma unroll
  for (int n = 0; n < 16; n++) H[n] = 0.f;
  char* base = (char*)uscr + (size_t)bh * NC * UROWB + 4096;
  float sN[16], PN;
  {
    float* S = (float*)base;
#pragma unroll
    for (int n = 0; n < 16; n++) sN[n] = S[lane * 16 + n];
    PN = ((const float*)(base + 4096))[hh];
  }
  for (int c = 0; c < NC; c++) {
    float sC[16], PC = PN;
#pragma unroll
    for (int n = 0; n < 16; n++) sC[n] = sN[n];
    if (c + 1 < NC) {
      char* slot = base + (size_t)(c + 1) * UROWB;
      float* S = (float*)slot;
#pragma unroll
      for (int n = 0; n < 16; n++) sN[n] = S[lane * 16 + n];
      PN = ((const float*)(slot + 4096))[hh];
    }
    float* S0 = (float*)(base + (size_t)c * UROWB);
#pragma unroll
    for (int n = 0; n < 16; n++) {
      float hn = H[n];
      S0[lane * 16 + n] = hn;
      H[n] = PC * hn + sC[n];
    }
  }
}

// ---------------- phase 3 (fused gate): re-scan chunk, g_raw = (yv + D*x)*silu(z)
__global__ __launch_bounds__(64) void scan_p3(const bf16* __restrict__ xs,
                                              const float* __restrict__ BC,
                                              const float* __restrict__ dtf,
                                              const float* __restrict__ A_log,
                                              const float* __restrict__ Dp,
                                              const bf16* __restrict__ u,
                                              bf16* __restrict__ g) {
  int c = blockIdx.x & 31, hg = (blockIdx.x >> 5) & 31, b = blockIdx.x >> 10;
  int lane = threadIdx.x, hh = lane >> 3;
  int h = hg * 8 + hh;
  float A = -__expf(A_log[h]);
  float D = Dp[h];
  const char* slot = (const char*)u + (size_t)blockIdx.x * UROWB + 4096;
  float st[16];
#pragma unroll
  for (int n = 0; n < 16; n++) st[n] = ((const float*)slot)[lane * 16 + n];
  size_t rb = (size_t)b * SEQ + (size_t)c * LC;
#pragma unroll 2
  for (int t = 0; t < LC; t++) {
    size_t row = rb + t;
    const float* bcrow = BC + row * 32;
    float dtv = dtf[row * NH + h];
    float x = (float)xs[row * DIN + hg * 64 + lane];
    float dA = __expf(dtv * A);
    float w = dtv * x;
    float yv = 0.f;
#pragma unroll
    for (int n = 0; n < 16; n++) {
      st[n] = st[n] * dA + w * bcrow[n];
      yv += st[n] * bcrow[16 + n];
    }
    float z = (float)u[row * DPROJ + hg * 64 + lane];
    float gg = (yv + D * x) * (z / (1.f + __expf(-z)));
    g[row * DIN + hg * 64 + lane] = (bf16)gg;
  }
}

extern "C" void kernel_launch(void* const* d_in, const int* in_sizes, int n_in,
                              void* d_out, int out_size, void* d_ws, size_t ws_size,
                              hipStream_t stream) {
  const float* x = (const float*)d_in[0];
  const float* lnw = (const float*)d_in[1];
  const float* lnb = (const float*)d_in[2];
  const float* Win = (const float*)d_in[3];
  const float* cw = (const float*)d_in[4];
  const float* cb = (const float*)d_in[5];
  const float* Alog = (const float*)d_in[6];
  const float* Dpv = (const float*)d_in[7];
  const float* dtb = (const float*)d_in[8];
  const float* rmsw = (const float*)d_in[9];
  const float* Wout = (const float*)d_in[10];
  float* out = (float*)d_out;

  char* ws = (char*)d_ws;
  bf16* u = (bf16*)(ws + 0);                     // [8192][4384] bf16
  bf16* xnb = (bf16*)(ws + 71827456);            // [8192][1024] bf16 (dead after GEMM1)
  bf16* WinT = (bf16*)(ws + 88604672);           // [4608][1024] bf16 (dead after GEMM1)
  bf16* gb = (bf16*)(ws + 71827456);             // [8192][2048] bf16 g_raw (reuses xnb+WinT)
  bf16* xsb = (bf16*)(ws + 105381888);           // [8192][2048] bf16
  float* BC = (float*)(ws + 138936320);          // [8192][32] f32
  float* dtf = (float*)(ws + 139984896);         // [8192][256] f32
  bf16* WoutT = (bf16*)(ws + 148373504);         // [1024][2048] bf16 (rms_w folded)

  transpose_both<<<dim3(64, 144, 2), dim3(32, 8), 0, stream>>>(Win, WinT, Wout, WoutT, rmsw);
  ln_kernel<<<MROWS, 256, 0, stream>>>(x, lnw, lnb, xnb);
  gemm1_8p<<<1536, 512, 0, stream>>>(xnb, WinT, u);
  conv_prep3<<<(MROWS * 292) / 256, 256, 0, stream>>>(u, cw, cb, dtb, xsb, BC, dtf);
  scan_p1<<<4096, 64, 0, stream>>>(xsb, BC, dtf, Alog, u);
  scan_p2<<<128, 64, 0, stream>>>(u);
  scan_p3<<<4096, 64, 0, stream>>>(xsb, BC, dtf, Alog, Dpv, u, gb);
  gemm2_8p<<<256, 512, 0, stream>>>(gb, WoutT, out, x);
}